// Round 17
// baseline (148.281 us; speedup 1.0000x reference)
//
#include <hip/hip_runtime.h>
#include <math.h>

// Problem constants (fixed by setup_inputs)
#define B 2
#define D 64
#define N 8192        // t*h*w = 8*32*32
#define T 8
#define HW 1024
#define NCH 8         // key chunks (512 blocks = 2/CU; R15 proved 3/CU spills)
#define KPC (N / NCH) // keys per chunk = 1024
#define KT 64         // key tile staged in LDS
#define NT (KPC / KT) // 16 tiles per chunk
#define QT 256        // q rows per block = 4 waves x 64 (4 frag groups/wave)
#define NQT (N / QT)  // 32 q-tiles
#define PTS 18        // column-major P scratch stride (R16; == R12 LDS cost,
                      // transpose is at its LDS floor in either orientation)

#define LOG2E 1.44269504f

typedef _Float16 half8 __attribute__((ext_vector_type(8)));
typedef _Float16 half4 __attribute__((ext_vector_type(4)));
typedef _Float16 half2 __attribute__((ext_vector_type(2)));
typedef float floatx4 __attribute__((ext_vector_type(4)));

// ---------------------------------------------------------------------------
// Projections -> f16, LDS-staged x (R17).  Ledger: post-R10 proj was still
// ~25-30us -- its 16x-redundant x re-read (256MB via L2/L3) dominated.  Now:
// block = 32 n's x all 64 d's; x[64][32] staged in LDS once (x traffic 16MB
// = 1x); thread (n, dgrp) computes 8 d's x 3 mats.  512 blocks = 2/CU.
// LDS bank check: xs[c][32+n] reads -> bank = n (distinct per lane), 2 dgrps
// same-address broadcast = free.  Q/K writes b128-coalesced.
// ---------------------------------------------------------------------------
__global__ __launch_bounds__(256)
void proj_kernel(const float* __restrict__ x,
                 const float* __restrict__ wq, const float* __restrict__ bq,
                 const float* __restrict__ wk, const float* __restrict__ bk,
                 const float* __restrict__ wv, const float* __restrict__ bv,
                 _Float16* __restrict__ Qh, _Float16* __restrict__ Kh,
                 _Float16* __restrict__ VTh) {
    __shared__ float xs[64][32];

    int bid = blockIdx.x;            // 512 blocks: (b, n-tile of 32)
    int b   = bid / (N / 32);
    int n0  = (bid % (N / 32)) * 32;

    int tid  = threadIdx.x;
    int nl   = tid & 31;             // n within tile
    int dg   = tid >> 5;             // d-group (8 groups x 8 d)
    int d0   = dg * 8;

    // Stage x[64][n0..n0+32) cooperatively: thread loads 8 (c, n) pairs,
    // coalesced over n (consecutive lanes -> consecutive n).
    {
        int cs = tid >> 5;           // 8 c's per thread, stride 8
        const float* xb = x + (size_t)b * 64 * N + n0 + nl;
#pragma unroll
        for (int k = 0; k < 8; ++k)
            xs[cs + 8 * k][nl] = xb[(size_t)(cs + 8 * k) * N];
    }
    __syncthreads();

    float aq[8], ak[8], av[8];
#pragma unroll
    for (int i = 0; i < 8; ++i) { aq[i] = bq[d0+i]; ak[i] = bk[d0+i]; av[i] = bv[d0+i]; }
#pragma unroll
    for (int c = 0; c < 64; ++c) {
        float xv = xs[c][nl];        // broadcast within same-n lanes
#pragma unroll
        for (int i = 0; i < 8; ++i) {
            aq[i] += wq[(d0 + i) * 64 + c] * xv;   // w: 8 addrs/wave, L1-hot
            ak[i] += wk[(d0 + i) * 64 + c] * xv;
            av[i] += wv[(d0 + i) * 64 + c] * xv;
        }
    }
    int n = n0 + nl;
    size_t rowb = ((size_t)b * N + n) * 64 + d0;
    half8 hq, hk;
    const float qs = 0.125f * LOG2E;   // 1/sqrt(64) * log2(e)
#pragma unroll
    for (int i = 0; i < 8; ++i) {
        hq[i] = (_Float16)(aq[i] * qs);
        hk[i] = (_Float16)ak[i];
    }
    *(half8*)(Qh + rowb) = hq;         // d-contiguous b128, coalesced over n
    *(half8*)(Kh + rowb) = hk;
#pragma unroll
    for (int i = 0; i < 8; ++i)
        VTh[((size_t)b * 64 + d0 + i) * N + n] = (_Float16)av[i];  // n-coalesced
}

// ---------------------------------------------------------------------------
// Flash attention, mfma_f32_16x16x32_f16, NO max-subtraction (|s| <= ~1.5).
// FROZEN at R16 (= R12-equal, 54.5us): multi-pipe saturated (issue ~78%,
// LDS ~69%); the P C->A transpose costs ~480 LDS cyc/wave-iter in either
// orientation (row-major 64w16+16r64 == col-major 32w32+64r16) -- at floor.
// ---------------------------------------------------------------------------
__global__ __launch_bounds__(256, 2)
void attn_kernel(const _Float16* __restrict__ Qh, const _Float16* __restrict__ Kh,
                 const _Float16* __restrict__ VTh,
                 _Float16* __restrict__ Opart, float* __restrict__ lpart) {
    __shared__ _Float16 Ks[2][64][72];
    __shared__ _Float16 VTs[2][64][72];

    int bid = blockIdx.x;
    int b   = bid / (NCH * NQT);
    int rem = bid % (NCH * NQT);
    int ch  = rem / NQT;               // adjacent blocks share a key-chunk (L2)
    int qt  = rem % NQT;
    int q0  = qt * QT;
    int kbase = ch * KPC;

    int tid  = threadIdx.x;
    int wave = tid >> 6;
    int lane = tid & 63;
    int L    = lane & 15;
    int quad = lane >> 4;

    // Persistent Q A-fragments: 4 row-groups x 2 k-halves (32 VGPR).
    half8 qa[4][2];
#pragma unroll
    for (int g = 0; g < 4; ++g) {
        const _Float16* qrow = Qh + ((size_t)b * N + q0 + wave * 64 + g * 16 + L) * 64;
        qa[g][0] = *(const half8*)(qrow + quad * 8);
        qa[g][1] = *(const half8*)(qrow + 32 + quad * 8);
    }

    floatx4 o[4][4];      // 64 acc regs
    floatx4 lacc[4];      // 16 acc regs
#pragma unroll
    for (int g = 0; g < 4; ++g) {
        lacc[g] = (floatx4)0.f;
#pragma unroll
        for (int s = 0; s < 4; ++s) o[g][s] = (floatx4)0.f;
    }

    // B-fragment of all-ones in column 0: l = P . ones
    half8 ones;
    {
        _Float16 v = (L == 0) ? (_Float16)1.0f : (_Float16)0.0f;
#pragma unroll
        for (int i = 0; i < 8; ++i) ones[i] = v;
    }

    int srow = tid >> 2, sseg = tid & 3;   // staging: 64 rows x 4 segs of 16 f16
    const _Float16* Kg = Kh  + (size_t)b * N * 64 + (size_t)sseg * 16;
    const _Float16* Vg = VTh + ((size_t)b * 64 + srow) * N + sseg * 16;

    half8 kr0, kr1, vr0, vr1;  // single prefetch set (16 VGPR)
    {
        const _Float16* kp = Kg + (size_t)(kbase + srow) * 64;
        kr0 = *(const half8*)(kp);
        kr1 = *(const half8*)(kp + 8);
        const _Float16* vp = Vg + kbase;
        vr0 = *(const half8*)(vp);
        vr1 = *(const half8*)(vp + 8);
    }
    *(half8*)(&Ks[0][srow][sseg * 16])      = kr0;
    *(half8*)(&Ks[0][srow][sseg * 16 + 8])  = kr1;
    *(half8*)(&VTs[0][srow][sseg * 16])     = vr0;
    *(half8*)(&VTs[0][srow][sseg * 16 + 8]) = vr1;
    __syncthreads();

    for (int kt = 0; kt < NT; ++kt) {
        int cur = kt & 1, nxt = cur ^ 1;
        bool more = (kt + 1 < NT);

        if (more) {
            int kb = kbase + (kt + 1) * KT;
            const _Float16* kp = Kg + (size_t)(kb + srow) * 64;
            kr0 = *(const half8*)(kp);
            kr1 = *(const half8*)(kp + 8);
            const _Float16* vp = Vg + kb;
            vr0 = *(const half8*)(vp);
            vr1 = *(const half8*)(vp + 8);
        }

        // Read K-tile and V-tile fragments ONCE (the per-wave minimum);
        // both q-pairs below consume these registers.
        half8 kf[4][2], vb[4][2];
#pragma unroll
        for (int sub = 0; sub < 4; ++sub) {
            kf[sub][0] = *(const half8*)(&Ks[cur][sub * 16 + L][quad * 8]);
            kf[sub][1] = *(const half8*)(&Ks[cur][sub * 16 + L][32 + quad * 8]);
            vb[sub][0] = *(const half8*)(&VTs[cur][sub * 16 + L][quad * 8]);
            vb[sub][1] = *(const half8*)(&VTs[cur][sub * 16 + L][32 + quad * 8]);
        }

        // Per-wave column-major P scratch regions (flat 1152 f16 each),
        // reused by both pairs.  Pt[col][row]: offset = col*PTS + row.
        _Float16* P0 = &Ks[nxt][wave * 16][0];
        _Float16* P1 = &VTs[nxt][wave * 16][0];

#pragma unroll
        for (int p = 0; p < 2; ++p) {
            // S = Q . K^T for groups 2p, 2p+1
            floatx4 s[2][4];
#pragma unroll
            for (int sub = 0; sub < 4; ++sub) {
#pragma unroll
                for (int gg = 0; gg < 2; ++gg) {
                    int g = 2 * p + gg;
                    floatx4 acc = (floatx4)0.f;
                    acc = __builtin_amdgcn_mfma_f32_16x16x32_f16(qa[g][0], kf[sub][0], acc, 0, 0, 0);
                    acc = __builtin_amdgcn_mfma_f32_16x16x32_f16(qa[g][1], kf[sub][1], acc, 0, 0, 0);
                    s[gg][sub] = acc;
                }
            }

            // P = exp2(S)
#pragma unroll
            for (int gg = 0; gg < 2; ++gg)
#pragma unroll
                for (int sub = 0; sub < 4; ++sub)
#pragma unroll
                    for (int r = 0; r < 4; ++r)
                        s[gg][sub][r] = __builtin_amdgcn_exp2f(s[gg][sub][r]);

            // P write, column-major: lane owns rows quad*4..+3 of column
            // sub*16+L -> two aligned b32 stores (bytes 36*col + 8*quad).
#pragma unroll
            for (int gg = 0; gg < 2; ++gg) {
                _Float16* Pb = gg ? P1 : P0;
#pragma unroll
                for (int sub = 0; sub < 4; ++sub) {
                    int cb = (sub * 16 + L) * PTS + quad * 4;
                    half2 w0 = {(_Float16)s[gg][sub][0], (_Float16)s[gg][sub][1]};
                    half2 w1 = {(_Float16)s[gg][sub][2], (_Float16)s[gg][sub][3]};
                    *(half2*)(&Pb[cb])     = w0;
                    *(half2*)(&Pb[cb + 2]) = w1;
                }
            }
            // P read, A-frag: pa[gg][h][j] = P[row=L][k=h*32+quad*8+j]
            //                              = Pt[k][L]  (b16, conflict-free)
            half8 pa[2][2];
#pragma unroll
            for (int gg = 0; gg < 2; ++gg) {
                const _Float16* Pb = gg ? P1 : P0;
#pragma unroll
                for (int h = 0; h < 2; ++h) {
                    half8 a;
#pragma unroll
                    for (int j = 0; j < 8; ++j)
                        a[j] = Pb[(h * 32 + quad * 8 + j) * PTS + L];
                    pa[gg][h] = a;
                }
            }

            // O += P . V ; l += P . ones
#pragma unroll
            for (int sub = 0; sub < 4; ++sub) {
#pragma unroll
                for (int gg = 0; gg < 2; ++gg) {
                    int g = 2 * p + gg;
                    o[g][sub] = __builtin_amdgcn_mfma_f32_16x16x32_f16(pa[gg][0], vb[sub][0], o[g][sub], 0, 0, 0);
                    o[g][sub] = __builtin_amdgcn_mfma_f32_16x16x32_f16(pa[gg][1], vb[sub][1], o[g][sub], 0, 0, 0);
                }
            }
#pragma unroll
            for (int gg = 0; gg < 2; ++gg) {
                int g = 2 * p + gg;
                lacc[g] = __builtin_amdgcn_mfma_f32_16x16x32_f16(pa[gg][0], ones, lacc[g], 0, 0, 0);
                lacc[g] = __builtin_amdgcn_mfma_f32_16x16x32_f16(pa[gg][1], ones, lacc[g], 0, 0, 0);
            }
        }

        // Stage prefetched tile (own wave's rows; P scratch already consumed)
        if (more) {
            *(half8*)(&Ks[nxt][srow][sseg * 16])      = kr0;
            *(half8*)(&Ks[nxt][srow][sseg * 16 + 8])  = kr1;
            *(half8*)(&VTs[nxt][srow][sseg * 16])     = vr0;
            *(half8*)(&VTs[nxt][srow][sseg * 16 + 8]) = vr1;
        }
        __syncthreads();
    }

    // Emit per-chunk partials (unnormalized O as f16, l as f32); merge = sum.
    size_t pb = (size_t)(b * NCH + ch) * N + q0 + wave * 64;
#pragma unroll
    for (int g = 0; g < 4; ++g)
#pragma unroll
        for (int sub = 0; sub < 4; ++sub)
#pragma unroll
            for (int r = 0; r < 4; ++r)
                Opart[(pb + g * 16 + quad * 4 + r) * 64 + sub * 16 + L] =
                    (_Float16)o[g][sub][r];
    if (L == 0) {
#pragma unroll
        for (int g = 0; g < 4; ++g)
#pragma unroll
            for (int r = 0; r < 4; ++r)
                lpart[pb + g * 16 + quad * 4 + r] = lacc[g][r];
    }
}

// ---------------------------------------------------------------------------
// Sum the NCH chunk partials (no max-merge needed) and sum over t.
// out[b, d, hw] = sum_t ( sum_c O / sum_c l )
// ---------------------------------------------------------------------------
__global__ void reduce_kernel(const _Float16* __restrict__ Opart,
                              const float* __restrict__ lpart,
                              float* __restrict__ out) {
    int g  = blockIdx.x * 256 + threadIdx.x;  // 131072 threads
    int d  = g & 63;
    int hw = (g >> 6) & (HW - 1);
    int b  = g >> 16;

    float acc = 0.f;
    for (int t = 0; t < T; ++t) {
        int row = t * HW + hw;
        float Lsum = 0.f, num = 0.f;
#pragma unroll
        for (int c = 0; c < NCH; ++c) {
            size_t pb = (size_t)(b * NCH + c) * N + row;
            Lsum += lpart[pb];
            num  += (float)Opart[pb * 64 + d];
        }
        acc += num / Lsum;
    }
    out[((size_t)b * D + d) * HW + hw] = acc;
}

// ---------------------------------------------------------------------------
extern "C" void kernel_launch(void* const* d_in, const int* in_sizes, int n_in,
                              void* d_out, int out_size, void* d_ws, size_t ws_size,
                              hipStream_t stream) {
    const float* x  = (const float*)d_in[0];
    const float* wq = (const float*)d_in[1];
    const float* bq = (const float*)d_in[2];
    const float* wk = (const float*)d_in[3];
    const float* bk = (const float*)d_in[4];
    const float* wv = (const float*)d_in[5];
    const float* bv = (const float*)d_in[6];

    const size_t QSZ = (size_t)B * N * 64;           // 1,048,576 f16 elems
    _Float16* Qh    = (_Float16*)d_ws;
    _Float16* Kh    = Qh + QSZ;
    _Float16* VTh   = Kh + QSZ;
    _Float16* Opart = VTh + QSZ;                     // B*NCH*N*64 f16 = 16.8 MB
    float*    lpart = (float*)(Opart + (size_t)B * NCH * N * 64);  // 512 KB

    proj_kernel<<<B * (N / 32), 256, 0, stream>>>(x, wq, bq, wk, bk, wv, bv,
                                                  Qh, Kh, VTh);
    attn_kernel<<<B * NCH * NQT, 256, 0, stream>>>(Qh, Kh, VTh, Opart, lpart);
    reduce_kernel<<<(B * HW * D) / 256, 256, 0, stream>>>(Opart, lpart, (float*)d_out);
}

// Round 18
// 137.684 us; speedup vs baseline: 1.0770x; 1.0770x over previous
//
#include <hip/hip_runtime.h>
#include <math.h>

// Problem constants (fixed by setup_inputs)
#define B 2
#define D 64
#define N 8192        // t*h*w = 8*32*32
#define T 8
#define HW 1024
#define NCH 8         // key chunks (512 blocks = 2/CU; R15 proved 3/CU spills)
#define KPC (N / NCH) // keys per chunk = 1024
#define KT 64         // key tile staged in LDS
#define NT (KPC / KT) // 16 tiles per chunk
#define QT 256        // q rows per block = 4 waves x 64 (4 frag groups/wave)
#define NQT (N / QT)  // 32 q-tiles
#define PTS 18        // column-major P scratch stride (R16)

#define LOG2E 1.44269504f

typedef _Float16 half8 __attribute__((ext_vector_type(8)));
typedef _Float16 half4 __attribute__((ext_vector_type(4)));
typedef _Float16 half2 __attribute__((ext_vector_type(2)));
typedef float floatx4 __attribute__((ext_vector_type(4)));

// ---------------------------------------------------------------------------
// Projections -> f16 (R10 version -- best measured).  4 d's/thread, 1024
// blocks, xcol[64] in registers = 64 independent coalesced loads (ILP) with
// 16 waves/CU (TLP).  x re-read 16x rides L2/L3 (x is 4MB, fully resident).
// R17's LDS-staged variant was +10us (serial LDS->FMA chains, 2 blocks/CU)
// -- reverted.
// ---------------------------------------------------------------------------
__global__ __launch_bounds__(256)
void proj_kernel(const float* __restrict__ x,
                 const float* __restrict__ wq, const float* __restrict__ bq,
                 const float* __restrict__ wk, const float* __restrict__ bk,
                 const float* __restrict__ wv, const float* __restrict__ bv,
                 _Float16* __restrict__ Qh, _Float16* __restrict__ Kh,
                 _Float16* __restrict__ VTh) {
    int n  = blockIdx.x * 256 + threadIdx.x;
    int d0 = blockIdx.y * 4;
    int b  = blockIdx.z;

    float xcol[64];
    const float* xb = x + (size_t)b * 64 * N + n;
#pragma unroll
    for (int c = 0; c < 64; ++c) xcol[c] = xb[(size_t)c * N];

    float aq[4], ak[4], av[4];
#pragma unroll
    for (int i = 0; i < 4; ++i) { aq[i] = bq[d0+i]; ak[i] = bk[d0+i]; av[i] = bv[d0+i]; }
#pragma unroll
    for (int c = 0; c < 64; ++c) {
        float xv = xcol[c];
#pragma unroll
        for (int i = 0; i < 4; ++i) {
            aq[i] += wq[(d0 + i) * 64 + c] * xv;
            ak[i] += wk[(d0 + i) * 64 + c] * xv;
            av[i] += wv[(d0 + i) * 64 + c] * xv;
        }
    }
    size_t rowb = ((size_t)b * N + n) * 64 + d0;
    half4 hq, hk;
    const float qs = 0.125f * LOG2E;   // 1/sqrt(64) * log2(e)
#pragma unroll
    for (int i = 0; i < 4; ++i) {
        hq[i] = (_Float16)(aq[i] * qs);
        hk[i] = (_Float16)ak[i];
    }
    *(half4*)(Qh + rowb) = hq;
    *(half4*)(Kh + rowb) = hk;
#pragma unroll
    for (int i = 0; i < 4; ++i)
        VTh[((size_t)b * 64 + d0 + i) * N + n] = (_Float16)av[i];
}

// ---------------------------------------------------------------------------
// Flash attention, mfma_f32_16x16x32_f16, NO max-subtraction (|s| <= ~1.5).
// FROZEN at R16 (54.5us): multi-pipe saturated (issue ~78%, LDS ~69%,
// MFMA 34%); the P C->A transpose costs ~480 LDS cyc/wave-iter in either
// orientation (row-major 64w16+16r64 == col-major 32w32+64r16) -- at floor.
// QT=256 (4 groups/wave), (256,2) = 2 blocks/CU ((256,3) spills -- R15),
// K/V frags read once/wave-iter, single-set prefetch, ones-column l-MFMA,
// ONE barrier/iter, column-major P scratch at PTS=18.
// ---------------------------------------------------------------------------
__global__ __launch_bounds__(256, 2)
void attn_kernel(const _Float16* __restrict__ Qh, const _Float16* __restrict__ Kh,
                 const _Float16* __restrict__ VTh,
                 _Float16* __restrict__ Opart, float* __restrict__ lpart) {
    __shared__ _Float16 Ks[2][64][72];
    __shared__ _Float16 VTs[2][64][72];

    int bid = blockIdx.x;
    int b   = bid / (NCH * NQT);
    int rem = bid % (NCH * NQT);
    int ch  = rem / NQT;               // adjacent blocks share a key-chunk (L2)
    int qt  = rem % NQT;
    int q0  = qt * QT;
    int kbase = ch * KPC;

    int tid  = threadIdx.x;
    int wave = tid >> 6;
    int lane = tid & 63;
    int L    = lane & 15;
    int quad = lane >> 4;

    // Persistent Q A-fragments: 4 row-groups x 2 k-halves (32 VGPR).
    half8 qa[4][2];
#pragma unroll
    for (int g = 0; g < 4; ++g) {
        const _Float16* qrow = Qh + ((size_t)b * N + q0 + wave * 64 + g * 16 + L) * 64;
        qa[g][0] = *(const half8*)(qrow + quad * 8);
        qa[g][1] = *(const half8*)(qrow + 32 + quad * 8);
    }

    floatx4 o[4][4];      // 64 acc regs
    floatx4 lacc[4];      // 16 acc regs
#pragma unroll
    for (int g = 0; g < 4; ++g) {
        lacc[g] = (floatx4)0.f;
#pragma unroll
        for (int s = 0; s < 4; ++s) o[g][s] = (floatx4)0.f;
    }

    // B-fragment of all-ones in column 0: l = P . ones
    half8 ones;
    {
        _Float16 v = (L == 0) ? (_Float16)1.0f : (_Float16)0.0f;
#pragma unroll
        for (int i = 0; i < 8; ++i) ones[i] = v;
    }

    int srow = tid >> 2, sseg = tid & 3;   // staging: 64 rows x 4 segs of 16 f16
    const _Float16* Kg = Kh  + (size_t)b * N * 64 + (size_t)sseg * 16;
    const _Float16* Vg = VTh + ((size_t)b * 64 + srow) * N + sseg * 16;

    half8 kr0, kr1, vr0, vr1;  // single prefetch set (16 VGPR)
    {
        const _Float16* kp = Kg + (size_t)(kbase + srow) * 64;
        kr0 = *(const half8*)(kp);
        kr1 = *(const half8*)(kp + 8);
        const _Float16* vp = Vg + kbase;
        vr0 = *(const half8*)(vp);
        vr1 = *(const half8*)(vp + 8);
    }
    *(half8*)(&Ks[0][srow][sseg * 16])      = kr0;
    *(half8*)(&Ks[0][srow][sseg * 16 + 8])  = kr1;
    *(half8*)(&VTs[0][srow][sseg * 16])     = vr0;
    *(half8*)(&VTs[0][srow][sseg * 16 + 8]) = vr1;
    __syncthreads();

    for (int kt = 0; kt < NT; ++kt) {
        int cur = kt & 1, nxt = cur ^ 1;
        bool more = (kt + 1 < NT);

        if (more) {
            int kb = kbase + (kt + 1) * KT;
            const _Float16* kp = Kg + (size_t)(kb + srow) * 64;
            kr0 = *(const half8*)(kp);
            kr1 = *(const half8*)(kp + 8);
            const _Float16* vp = Vg + kb;
            vr0 = *(const half8*)(vp);
            vr1 = *(const half8*)(vp + 8);
        }

        // Read K-tile and V-tile fragments ONCE (the per-wave minimum);
        // both q-pairs below consume these registers.
        half8 kf[4][2], vb[4][2];
#pragma unroll
        for (int sub = 0; sub < 4; ++sub) {
            kf[sub][0] = *(const half8*)(&Ks[cur][sub * 16 + L][quad * 8]);
            kf[sub][1] = *(const half8*)(&Ks[cur][sub * 16 + L][32 + quad * 8]);
            vb[sub][0] = *(const half8*)(&VTs[cur][sub * 16 + L][quad * 8]);
            vb[sub][1] = *(const half8*)(&VTs[cur][sub * 16 + L][32 + quad * 8]);
        }

        // Per-wave column-major P scratch regions (flat 1152 f16 each),
        // reused by both pairs.  Pt[col][row]: offset = col*PTS + row.
        _Float16* P0 = &Ks[nxt][wave * 16][0];
        _Float16* P1 = &VTs[nxt][wave * 16][0];

#pragma unroll
        for (int p = 0; p < 2; ++p) {
            // S = Q . K^T for groups 2p, 2p+1
            floatx4 s[2][4];
#pragma unroll
            for (int sub = 0; sub < 4; ++sub) {
#pragma unroll
                for (int gg = 0; gg < 2; ++gg) {
                    int g = 2 * p + gg;
                    floatx4 acc = (floatx4)0.f;
                    acc = __builtin_amdgcn_mfma_f32_16x16x32_f16(qa[g][0], kf[sub][0], acc, 0, 0, 0);
                    acc = __builtin_amdgcn_mfma_f32_16x16x32_f16(qa[g][1], kf[sub][1], acc, 0, 0, 0);
                    s[gg][sub] = acc;
                }
            }

            // P = exp2(S)
#pragma unroll
            for (int gg = 0; gg < 2; ++gg)
#pragma unroll
                for (int sub = 0; sub < 4; ++sub)
#pragma unroll
                    for (int r = 0; r < 4; ++r)
                        s[gg][sub][r] = __builtin_amdgcn_exp2f(s[gg][sub][r]);

            // P write, column-major: lane owns rows quad*4..+3 of column
            // sub*16+L -> two aligned b32 stores (bytes 36*col + 8*quad).
#pragma unroll
            for (int gg = 0; gg < 2; ++gg) {
                _Float16* Pb = gg ? P1 : P0;
#pragma unroll
                for (int sub = 0; sub < 4; ++sub) {
                    int cb = (sub * 16 + L) * PTS + quad * 4;
                    half2 w0 = {(_Float16)s[gg][sub][0], (_Float16)s[gg][sub][1]};
                    half2 w1 = {(_Float16)s[gg][sub][2], (_Float16)s[gg][sub][3]};
                    *(half2*)(&Pb[cb])     = w0;
                    *(half2*)(&Pb[cb + 2]) = w1;
                }
            }
            // P read, A-frag: pa[gg][h][j] = P[row=L][k=h*32+quad*8+j]
            //                              = Pt[k][L]  (b16, conflict-free)
            half8 pa[2][2];
#pragma unroll
            for (int gg = 0; gg < 2; ++gg) {
                const _Float16* Pb = gg ? P1 : P0;
#pragma unroll
                for (int h = 0; h < 2; ++h) {
                    half8 a;
#pragma unroll
                    for (int j = 0; j < 8; ++j)
                        a[j] = Pb[(h * 32 + quad * 8 + j) * PTS + L];
                    pa[gg][h] = a;
                }
            }

            // O += P . V ; l += P . ones
#pragma unroll
            for (int sub = 0; sub < 4; ++sub) {
#pragma unroll
                for (int gg = 0; gg < 2; ++gg) {
                    int g = 2 * p + gg;
                    o[g][sub] = __builtin_amdgcn_mfma_f32_16x16x32_f16(pa[gg][0], vb[sub][0], o[g][sub], 0, 0, 0);
                    o[g][sub] = __builtin_amdgcn_mfma_f32_16x16x32_f16(pa[gg][1], vb[sub][1], o[g][sub], 0, 0, 0);
                }
            }
#pragma unroll
            for (int gg = 0; gg < 2; ++gg) {
                int g = 2 * p + gg;
                lacc[g] = __builtin_amdgcn_mfma_f32_16x16x32_f16(pa[gg][0], ones, lacc[g], 0, 0, 0);
                lacc[g] = __builtin_amdgcn_mfma_f32_16x16x32_f16(pa[gg][1], ones, lacc[g], 0, 0, 0);
            }
        }

        // Stage prefetched tile (own wave's rows; P scratch already consumed)
        if (more) {
            *(half8*)(&Ks[nxt][srow][sseg * 16])      = kr0;
            *(half8*)(&Ks[nxt][srow][sseg * 16 + 8])  = kr1;
            *(half8*)(&VTs[nxt][srow][sseg * 16])     = vr0;
            *(half8*)(&VTs[nxt][srow][sseg * 16 + 8]) = vr1;
        }
        __syncthreads();
    }

    // Emit per-chunk partials (unnormalized O as f16, l as f32); merge = sum.
    size_t pb = (size_t)(b * NCH + ch) * N + q0 + wave * 64;
#pragma unroll
    for (int g = 0; g < 4; ++g)
#pragma unroll
        for (int sub = 0; sub < 4; ++sub)
#pragma unroll
            for (int r = 0; r < 4; ++r)
                Opart[(pb + g * 16 + quad * 4 + r) * 64 + sub * 16 + L] =
                    (_Float16)o[g][sub][r];
    if (L == 0) {
#pragma unroll
        for (int g = 0; g < 4; ++g)
#pragma unroll
            for (int r = 0; r < 4; ++r)
                lpart[pb + g * 16 + quad * 4 + r] = lacc[g][r];
    }
}

// ---------------------------------------------------------------------------
// Sum the NCH chunk partials (no max-merge needed) and sum over t.
// out[b, d, hw] = sum_t ( sum_c O / sum_c l )
// ---------------------------------------------------------------------------
__global__ void reduce_kernel(const _Float16* __restrict__ Opart,
                              const float* __restrict__ lpart,
                              float* __restrict__ out) {
    int g  = blockIdx.x * 256 + threadIdx.x;  // 131072 threads
    int d  = g & 63;
    int hw = (g >> 6) & (HW - 1);
    int b  = g >> 16;

    float acc = 0.f;
    for (int t = 0; t < T; ++t) {
        int row = t * HW + hw;
        float Lsum = 0.f, num = 0.f;
#pragma unroll
        for (int c = 0; c < NCH; ++c) {
            size_t pb = (size_t)(b * NCH + c) * N + row;
            Lsum += lpart[pb];
            num  += (float)Opart[pb * 64 + d];
        }
        acc += num / Lsum;
    }
    out[((size_t)b * D + d) * HW + hw] = acc;
}

// ---------------------------------------------------------------------------
extern "C" void kernel_launch(void* const* d_in, const int* in_sizes, int n_in,
                              void* d_out, int out_size, void* d_ws, size_t ws_size,
                              hipStream_t stream) {
    const float* x  = (const float*)d_in[0];
    const float* wq = (const float*)d_in[1];
    const float* bq = (const float*)d_in[2];
    const float* wk = (const float*)d_in[3];
    const float* bk = (const float*)d_in[4];
    const float* wv = (const float*)d_in[5];
    const float* bv = (const float*)d_in[6];

    const size_t QSZ = (size_t)B * N * 64;           // 1,048,576 f16 elems
    _Float16* Qh    = (_Float16*)d_ws;
    _Float16* Kh    = Qh + QSZ;
    _Float16* VTh   = Kh + QSZ;
    _Float16* Opart = VTh + QSZ;                     // B*NCH*N*64 f16 = 16.8 MB
    float*    lpart = (float*)(Opart + (size_t)B * NCH * N * 64);  // 512 KB

    proj_kernel<<<dim3(N / 256, 16, B), 256, 0, stream>>>(x, wq, bq, wk, bk, wv, bv,
                                                          Qh, Kh, VTh);
    attn_kernel<<<B * NCH * NQT, 256, 0, stream>>>(Qh, Kh, VTh, Opart, lpart);
    reduce_kernel<<<(B * HW * D) / 256, 256, 0, stream>>>(Opart, lpart, (float*)d_out);
}